// Round 4
// baseline (355.340 us; speedup 1.0000x reference)
//
#include <hip/hip_runtime.h>
#include <math.h>

#define BB 2
#define NN 4096
#define DIM 128
#define DIN 256
#define DST 16
#define DTR 8
#define NROW (BB*NN)          // 8192
#define SOUT (BB*NN*DIM)      // 1048576
#define NC 64                 // chunks per sequence
#define CL 64                 // chunk length (NC*CL == NN)
#define EPSF 1e-5f

__device__ __forceinline__ float siluf(float x){ return x / (1.f + __expf(-x)); }
__device__ __forceinline__ float softplusf(float x){ return fmaxf(x,0.f) + log1pf(__expf(-fabsf(x))); }

// ---------------- K1: residual add + LN + channel swap ----------------
__global__ void k_ln_swap(const float* __restrict__ I1, const float* __restrict__ I2,
                          const float* __restrict__ I1r, const float* __restrict__ I2r,
                          const float* __restrict__ w1, const float* __restrict__ b1,
                          const float* __restrict__ w2, const float* __restrict__ b2,
                          float* __restrict__ out, float* __restrict__ xs1, float* __restrict__ xs2){
  const int row = blockIdx.x;
  const int tid = threadIdx.x;
  const int d0 = tid, d1 = tid + 64;
  const int base = row * DIM;
  float r1a = I1[base+d0] + I1r[base+d0];
  float r1b = I1[base+d1] + I1r[base+d1];
  float r2a = I2[base+d0] + I2r[base+d0];
  float r2b = I2[base+d1] + I2r[base+d1];
  out[2*SOUT+base+d0]=r1a; out[2*SOUT+base+d1]=r1b;
  out[3*SOUT+base+d0]=r2a; out[3*SOUT+base+d1]=r2b;
  float s1=r1a+r1b, q1=fmaf(r1a,r1a,r1b*r1b);
  float s2=r2a+r2b, q2=fmaf(r2a,r2a,r2b*r2b);
  #pragma unroll
  for (int m=32;m;m>>=1){
    s1+=__shfl_xor(s1,m,64); q1+=__shfl_xor(q1,m,64);
    s2+=__shfl_xor(s2,m,64); q2+=__shfl_xor(q2,m,64);
  }
  const float inv = 1.f/128.f;
  float mu1=s1*inv, mu2=s2*inv;
  float var1=q1*inv-mu1*mu1, var2=q2*inv-mu2*mu2;
  float is1=rsqrtf(var1+EPSF), is2=rsqrtf(var2+EPSF);
  float n1a=(r1a-mu1)*is1*w1[d0]+b1[d0];
  float n1b=(r1b-mu1)*is1*w1[d1]+b1[d1];
  float n2a=(r2a-mu2)*is2*w2[d0]+b2[d0];
  float n2b=(r2b-mu2)*is2*w2[d1]+b2[d1];
  bool e0 = (d0 & 1) == 0;
  xs1[base+d0] = e0 ? n2a : n1a;  xs1[base+d1] = e0 ? n2b : n1b;
  xs2[base+d0] = e0 ? n1a : n2a;  xs2[base+d1] = e0 ? n1b : n2b;
}

// ---------------- K2: xz = x @ W_in (128 -> 512), 16 rows/block ----------------
// x read via block-uniform global loads (scalar-load friendly); W once per block.
__global__ void k_inproj(const float* __restrict__ xs1, const float* __restrict__ xs2,
                         const float* __restrict__ Win1, const float* __restrict__ Win2,
                         float* __restrict__ xz){
  const int rb = blockIdx.x;            // 16 rows
  const int s = blockIdx.y;
  const int tid = threadIdx.x;          // 0..255 -> cols 2t,2t+1
  const float* x = (s ? xs2 : xs1) + (size_t)rb*16*DIM;
  const float2* W2 = (const float2*)(s ? Win2 : Win1);
  float ax[16], ay[16];
  #pragma unroll
  for (int r=0;r<16;r++){ ax[r]=0.f; ay[r]=0.f; }
  #pragma unroll 2
  for (int k4=0;k4<DIM/4;k4++){
    float2 w0 = W2[(4*k4+0)*256+tid];
    float2 w1 = W2[(4*k4+1)*256+tid];
    float2 w2 = W2[(4*k4+2)*256+tid];
    float2 w3 = W2[(4*k4+3)*256+tid];
    #pragma unroll
    for (int r=0;r<16;r++){
      float4 xv = *(const float4*)&x[r*DIM + 4*k4];   // block-uniform
      ax[r] = fmaf(xv.x, w0.x, ax[r]); ay[r] = fmaf(xv.x, w0.y, ay[r]);
      ax[r] = fmaf(xv.y, w1.x, ax[r]); ay[r] = fmaf(xv.y, w1.y, ay[r]);
      ax[r] = fmaf(xv.z, w2.x, ax[r]); ay[r] = fmaf(xv.z, w2.y, ay[r]);
      ax[r] = fmaf(xv.w, w3.x, ax[r]); ay[r] = fmaf(xv.w, w3.y, ay[r]);
    }
  }
  #pragma unroll
  for (int r=0;r<16;r++){
    float2* o = (float2*)(xz + (size_t)s*NROW*512 + (size_t)(rb*16+r)*512);
    o[tid] = make_float2(ax[r], ay[r]);
  }
}

// ---------------- K3: depthwise conv4 + silu, x_dbl = xc@W_x, dt ----------------
__global__ void k_conv_proj(const float* __restrict__ xz,
                            const float* __restrict__ cw1, const float* __restrict__ cb1,
                            const float* __restrict__ Wx1, const float* __restrict__ Wdt1,
                            const float* __restrict__ dtb1,
                            const float* __restrict__ cw2, const float* __restrict__ cb2,
                            const float* __restrict__ Wx2, const float* __restrict__ Wdt2,
                            const float* __restrict__ dtb2,
                            float* __restrict__ xc, float* __restrict__ xd, float* __restrict__ dtg){
  const int row = blockIdx.x;
  const int s = blockIdx.y;
  const int tid = threadIdx.x;
  const int b = row >> 12, t = row & (NN-1);
  const float* xzq = xz + (size_t)s*NROW*512;
  float* xcq = xc + (size_t)s*NROW*256;
  float* xdq = xd + (size_t)s*NROW*40;
  float* dtq = dtg + (size_t)s*NROW*256;
  const float* cw = s?cw2:cw1; const float* cb = s?cb2:cb1;
  const float* Wx = s?Wx2:Wx1; const float* Wdt = s?Wdt2:Wdt1; const float* dtb = s?dtb2:dtb1;
  __shared__ __align__(16) float xcs[DIN];
  __shared__ float xds[40];
  #pragma unroll
  for (int j=0;j<4;j++){
    int d = tid + 64*j;
    float acc = cb[d];
    #pragma unroll
    for (int k=0;k<4;k++){
      int tt = t - 3 + k;
      if (tt >= 0) acc = fmaf(xzq[(size_t)(b*NN+tt)*512 + d], cw[d*4+k], acc);
    }
    float v = siluf(acc);
    xcs[d] = v;
    xcq[(size_t)row*256 + d] = v;
  }
  __syncthreads();
  if (tid < 40){
    float acc = 0.f;
    #pragma unroll 8
    for (int k4=0;k4<DIN/4;k4++){
      float4 vv = *(const float4*)&xcs[4*k4];
      acc = fmaf(vv.x, Wx[(4*k4+0)*40+tid], acc);
      acc = fmaf(vv.y, Wx[(4*k4+1)*40+tid], acc);
      acc = fmaf(vv.z, Wx[(4*k4+2)*40+tid], acc);
      acc = fmaf(vv.w, Wx[(4*k4+3)*40+tid], acc);
    }
    xds[tid] = acc;
    xdq[(size_t)row*40 + tid] = acc;
  }
  __syncthreads();
  #pragma unroll
  for (int j=0;j<4;j++){
    int d = tid + 64*j;
    float acc = dtb[d];
    #pragma unroll
    for (int r=0;r<DTR;r++) acc = fmaf(xds[r], Wdt[r*256+d], acc);
    dtq[(size_t)row*256 + d] = softplusf(acc);
  }
}

// ---------------- K4a: local chunk scan (hybrid layout) ----------------
// grid: (NC, 4 dtiles, 4 sb), 256 threads = 64 d x 4 si-groups; lane owns 4 states.
__global__ void k_scan_local(const float* __restrict__ dtg, const float* __restrict__ xc,
                             const float* __restrict__ xd,
                             const float* __restrict__ Alog1, const float* __restrict__ Alog2,
                             float* __restrict__ Aprod, float* __restrict__ Sfin){
  const int c = blockIdx.x, dtile = blockIdx.y, sb = blockIdx.z;
  const int s = sb >> 1, b = sb & 1;
  const int tid = threadIdx.x;
  const int sq = tid & 3, dl = tid >> 2;
  const int d = dtile*64 + dl;
  const float* dtp = dtg + (size_t)s*NROW*256 + (size_t)b*NN*256 + (size_t)c*CL*256 + d;
  const float* xcp = xc  + (size_t)s*NROW*256 + (size_t)b*NN*256 + (size_t)c*CL*256 + d;
  const float* xdp = xd  + (size_t)s*NROW*40  + (size_t)b*NN*40  + (size_t)c*CL*40 + 8 + 4*sq;
  const float* Alog = s?Alog2:Alog1;
  float A0 = -__expf(Alog[d*16 + 4*sq + 0]);
  float A1 = -__expf(Alog[d*16 + 4*sq + 1]);
  float A2 = -__expf(Alog[d*16 + 4*sq + 2]);
  float A3 = -__expf(Alog[d*16 + 4*sq + 3]);
  float h0=0.f,h1=0.f,h2=0.f,h3=0.f,sdt=0.f;
  #pragma unroll 4
  for (int tt=0;tt<CL;tt++){
    float dtv = dtp[tt*256];
    float xcv = xcp[tt*256];
    float4 bm = *(const float4*)(xdp + tt*40);
    float coef = dtv*xcv;
    sdt += dtv;
    h0 = fmaf(__expf(dtv*A0), h0, coef*bm.x);
    h1 = fmaf(__expf(dtv*A1), h1, coef*bm.y);
    h2 = fmaf(__expf(dtv*A2), h2, coef*bm.z);
    h3 = fmaf(__expf(dtv*A3), h3, coef*bm.w);
  }
  const size_t idx = ((size_t)(sb*NC + c)*256 + d)*16 + 4*sq;
  *(float4*)&Aprod[idx] = make_float4(__expf(A0*sdt),__expf(A1*sdt),__expf(A2*sdt),__expf(A3*sdt));
  *(float4*)&Sfin[idx]  = make_float4(h0,h1,h2,h3);
}

// ---------------- K4b: inter-chunk carry ----------------
__global__ void k_scan_carry(const float* __restrict__ Aprod, const float* __restrict__ Sfin,
                             float* __restrict__ Hinit){
  const int g = blockIdx.x*256 + threadIdx.x;
  const int sb = g >> 12;
  const int rem = g & 4095;           // d*16+si
  float h = 0.f;
  #pragma unroll 4
  for (int c=0;c<NC;c++){
    const size_t idx = (size_t)(sb*NC + c)*4096 + rem;
    float A = Aprod[idx];
    float S = Sfin[idx];
    Hinit[idx] = h;
    h = fmaf(A, h, S);
  }
}

// ---------------- K4c: final chunk scan + y + fused epilogue elementwise ------
// writes v = (y + xc*D)*silu(z) into the xp half of xz.
__global__ void k_scan_final(const float* __restrict__ dtg, const float* __restrict__ xc,
                             const float* __restrict__ xd,
                             const float* __restrict__ Alog1, const float* __restrict__ Alog2,
                             const float* __restrict__ D1, const float* __restrict__ D2,
                             const float* __restrict__ Hinit, float* __restrict__ xz){
  const int c = blockIdx.x, dtile = blockIdx.y, sb = blockIdx.z;
  const int s = sb >> 1, b = sb & 1;
  const int tid = threadIdx.x;
  const int sq = tid & 3, dl = tid >> 2;
  const int d = dtile*64 + dl;
  const float* dtp = dtg + (size_t)s*NROW*256 + (size_t)b*NN*256 + (size_t)c*CL*256 + d;
  const float* xcp = xc  + (size_t)s*NROW*256 + (size_t)b*NN*256 + (size_t)c*CL*256 + d;
  const float* xdp = xd  + (size_t)s*NROW*40  + (size_t)b*NN*40  + (size_t)c*CL*40 + 8 + 4*sq;
  float* yq = xz + (size_t)s*NROW*512 + (size_t)b*NN*512 + (size_t)c*CL*512;
  const float* Alog = s?Alog2:Alog1;
  const float Dd = (s?D2:D1)[d];
  float A0 = -__expf(Alog[d*16 + 4*sq + 0]);
  float A1 = -__expf(Alog[d*16 + 4*sq + 1]);
  float A2 = -__expf(Alog[d*16 + 4*sq + 2]);
  float A3 = -__expf(Alog[d*16 + 4*sq + 3]);
  float4 hv = *(const float4*)&Hinit[((size_t)(sb*NC + c)*256 + d)*16 + 4*sq];
  float h0=hv.x,h1=hv.y,h2=hv.z,h3=hv.w;
  #pragma unroll 4
  for (int tt=0;tt<CL;tt++){
    float dtv = dtp[tt*256];
    float xcv = xcp[tt*256];
    float4 bm = *(const float4*)(xdp + tt*40);
    float4 cm = *(const float4*)(xdp + tt*40 + 16);
    float coef = dtv*xcv;
    h0 = fmaf(__expf(dtv*A0), h0, coef*bm.x);
    h1 = fmaf(__expf(dtv*A1), h1, coef*bm.y);
    h2 = fmaf(__expf(dtv*A2), h2, coef*bm.z);
    h3 = fmaf(__expf(dtv*A3), h3, coef*bm.w);
    float y = h0*cm.x + h1*cm.y + h2*cm.z + h3*cm.w;
    y += __shfl_xor(y, 1, 4);
    y += __shfl_xor(y, 2, 4);
    if (sq == 0){
      float zv = yq[tt*512 + 256 + d];
      yq[tt*512 + d] = fmaf(xcv, Dd, y) * siluf(zv);
    }
  }
}

// ---------------- K5: out = v @ W_out, 8 rows/block (v precomputed) ----------
__global__ void k_out(const float* __restrict__ xz,
                      const float* __restrict__ Wo1, const float* __restrict__ Wo2,
                      float* __restrict__ out){
  const int rb = blockIdx.x;
  const int s = blockIdx.y;
  const int tid = threadIdx.x;
  const int col = tid & 127, rh = tid >> 7;
  const float* vb = xz + (size_t)s*NROW*512 + (size_t)rb*8*512;
  const float* Wo = s?Wo2:Wo1;
  float acc[4] = {0.f,0.f,0.f,0.f};
  #pragma unroll 4
  for (int k4=0;k4<DIN/4;k4++){
    float w0 = Wo[(4*k4+0)*128+col];
    float w1 = Wo[(4*k4+1)*128+col];
    float w2 = Wo[(4*k4+2)*128+col];
    float w3 = Wo[(4*k4+3)*128+col];
    #pragma unroll
    for (int j=0;j<4;j++){
      float4 vv = *(const float4*)&vb[(size_t)(rh*4+j)*512 + 4*k4];  // wave-uniform
      acc[j] = fmaf(vv.x, w0, acc[j]);
      acc[j] = fmaf(vv.y, w1, acc[j]);
      acc[j] = fmaf(vv.z, w2, acc[j]);
      acc[j] = fmaf(vv.w, w3, acc[j]);
    }
  }
  #pragma unroll
  for (int j=0;j<4;j++)
    out[(size_t)s*SOUT + (size_t)(rb*8 + rh*4 + j)*128 + col] = acc[j];
}

extern "C" void kernel_launch(void* const* d_in, const int* in_sizes, int n_in,
                              void* d_out, int out_size, void* d_ws, size_t ws_size,
                              hipStream_t stream) {
  const float* I1   = (const float*)d_in[0];
  const float* I2   = (const float*)d_in[1];
  const float* I1r  = (const float*)d_in[2];
  const float* I2r  = (const float*)d_in[3];
  const float* ln1w = (const float*)d_in[4];
  const float* ln1b = (const float*)d_in[5];
  const float* ln2w = (const float*)d_in[6];
  const float* ln2b = (const float*)d_in[7];
  const float* Win1 = (const float*)d_in[8];
  const float* cw1  = (const float*)d_in[9];
  const float* cb1  = (const float*)d_in[10];
  const float* Wx1  = (const float*)d_in[11];
  const float* Wdt1 = (const float*)d_in[12];
  const float* dtb1 = (const float*)d_in[13];
  const float* Al1  = (const float*)d_in[14];
  const float* D1   = (const float*)d_in[15];
  const float* Wo1  = (const float*)d_in[16];
  const float* Win2 = (const float*)d_in[17];
  const float* cw2  = (const float*)d_in[18];
  const float* cb2  = (const float*)d_in[19];
  const float* Wx2  = (const float*)d_in[20];
  const float* Wdt2 = (const float*)d_in[21];
  const float* dtb2 = (const float*)d_in[22];
  const float* Al2  = (const float*)d_in[23];
  const float* D2   = (const float*)d_in[24];
  const float* Wo2  = (const float*)d_in[25];
  float* out = (float*)d_out;

  float* ws  = (float*)d_ws;
  float* xs1 = ws;                                  // 1M floats
  float* xs2 = xs1 + (size_t)SOUT;                  // 1M floats
  float* xz  = xs2 + (size_t)SOUT;                  // 8M floats
  float* xc  = xz  + (size_t)2*NROW*512;            // 4M floats
  float* xd  = xc  + (size_t)2*NROW*256;            // 640K floats
  float* dtg = xd  + (size_t)2*NROW*40;             // 4M floats
  float* Aprod = xs1;                               // overlay (dead after inproj)
  float* Sfin  = xs2;
  float* Hinit = out;                               // scratch until k_out

  k_ln_swap<<<dim3(NROW), dim3(64), 0, stream>>>(I1, I2, I1r, I2r, ln1w, ln1b, ln2w, ln2b,
                                                 out, xs1, xs2);
  k_inproj<<<dim3(NROW/16,2), dim3(256), 0, stream>>>(xs1, xs2, Win1, Win2, xz);
  k_conv_proj<<<dim3(NROW,2), dim3(64), 0, stream>>>(xz, cw1, cb1, Wx1, Wdt1, dtb1,
                                                     cw2, cb2, Wx2, Wdt2, dtb2,
                                                     xc, xd, dtg);
  k_scan_local<<<dim3(NC,4,4), dim3(256), 0, stream>>>(dtg, xc, xd, Al1, Al2, Aprod, Sfin);
  k_scan_carry<<<dim3(64), dim3(256), 0, stream>>>(Aprod, Sfin, Hinit);
  k_scan_final<<<dim3(NC,4,4), dim3(256), 0, stream>>>(dtg, xc, xd, Al1, Al2, D1, D2, Hinit, xz);
  k_out<<<dim3(NROW/8,2), dim3(256), 0, stream>>>(xz, Wo1, Wo2, out);
}

// Round 5
// 272.083 us; speedup vs baseline: 1.3060x; 1.3060x over previous
//
#include <hip/hip_runtime.h>
#include <hip/hip_bf16.h>
#include <math.h>

#define BB 2
#define NN 4096
#define DIM 128
#define DIN 256
#define DST 16
#define DTR 8
#define NROW (BB*NN)          // 8192
#define SOUT (BB*NN*DIM)      // 1048576
#define NC 64                 // chunks per sequence
#define CL 64                 // chunk length
#define XDP 48                // xd row pitch (40 used + 8 pad)
#define EPSF 1e-5f

typedef __hip_bfloat16 bf16;
typedef __attribute__((ext_vector_type(8))) short short8;     // 8 bf16 (4 VGPR)
typedef __attribute__((ext_vector_type(16))) float f32x16;
typedef __attribute__((ext_vector_type(4))) float f32x4;

__device__ __forceinline__ float siluf(float x){ return x / (1.f + __expf(-x)); }
__device__ __forceinline__ float softplusf(float x){ return fmaxf(x,0.f) + log1pf(__expf(-fabsf(x))); }
__device__ __forceinline__ float b2f(bf16 x){ return __bfloat162float(x); }
__device__ __forceinline__ bf16 f2b(float x){ return __float2bfloat16(x); }

// ---------------- K0: weights -> bf16, transposed to [N][K] ----------------
#define WIN_SZ (512*128)
#define WOUT_SZ (128*256)
#define WX_SZ (48*256)
__global__ void k_wconv(const float* __restrict__ Win1, const float* __restrict__ Win2,
                        const float* __restrict__ Wo1,  const float* __restrict__ Wo2,
                        const float* __restrict__ Wx1,  const float* __restrict__ Wx2,
                        bf16* __restrict__ Wt_in, bf16* __restrict__ Wt_out, bf16* __restrict__ Wt_x){
  int id = blockIdx.x*256 + threadIdx.x;
  if (id < 2*WIN_SZ){
    int s = id / WIN_SZ, r = id % WIN_SZ;
    int n = r >> 7, k = r & 127;                 // W_in shape 128x512
    Wt_in[id] = f2b((s?Win2:Win1)[k*512 + n]);
  } else if (id < 2*WIN_SZ + 2*WOUT_SZ){
    int j = id - 2*WIN_SZ;
    int s = j / WOUT_SZ, r = j % WOUT_SZ;
    int n = r >> 8, k = r & 255;                 // W_out shape 256x128
    Wt_out[j] = f2b((s?Wo2:Wo1)[k*128 + n]);
  } else if (id < 2*WIN_SZ + 2*WOUT_SZ + 2*WX_SZ){
    int j = id - 2*WIN_SZ - 2*WOUT_SZ;
    int s = j / WX_SZ, r = j % WX_SZ;
    int n = r >> 8, k = r & 255;                 // W_x shape 256x40, pad n>=40 with 0
    Wt_x[j] = f2b(n < 40 ? (s?Wx2:Wx1)[k*40 + n] : 0.f);
  }
}

// ---------------- K1: residual add + LN + channel swap (xs -> bf16) --------
__global__ void k_ln_swap(const float* __restrict__ I1, const float* __restrict__ I2,
                          const float* __restrict__ I1r, const float* __restrict__ I2r,
                          const float* __restrict__ w1, const float* __restrict__ b1,
                          const float* __restrict__ w2, const float* __restrict__ b2,
                          float* __restrict__ out, bf16* __restrict__ xs1, bf16* __restrict__ xs2){
  const int row = blockIdx.x;
  const int tid = threadIdx.x;
  const int d0 = tid, d1 = tid + 64;
  const int base = row * DIM;
  float r1a = I1[base+d0] + I1r[base+d0];
  float r1b = I1[base+d1] + I1r[base+d1];
  float r2a = I2[base+d0] + I2r[base+d0];
  float r2b = I2[base+d1] + I2r[base+d1];
  out[2*SOUT+base+d0]=r1a; out[2*SOUT+base+d1]=r1b;
  out[3*SOUT+base+d0]=r2a; out[3*SOUT+base+d1]=r2b;
  float s1=r1a+r1b, q1=fmaf(r1a,r1a,r1b*r1b);
  float s2=r2a+r2b, q2=fmaf(r2a,r2a,r2b*r2b);
  #pragma unroll
  for (int m=32;m;m>>=1){
    s1+=__shfl_xor(s1,m,64); q1+=__shfl_xor(q1,m,64);
    s2+=__shfl_xor(s2,m,64); q2+=__shfl_xor(q2,m,64);
  }
  const float inv = 1.f/128.f;
  float mu1=s1*inv, mu2=s2*inv;
  float var1=q1*inv-mu1*mu1, var2=q2*inv-mu2*mu2;
  float is1=rsqrtf(var1+EPSF), is2=rsqrtf(var2+EPSF);
  float n1a=(r1a-mu1)*is1*w1[d0]+b1[d0];
  float n1b=(r1b-mu1)*is1*w1[d1]+b1[d1];
  float n2a=(r2a-mu2)*is2*w2[d0]+b2[d0];
  float n2b=(r2b-mu2)*is2*w2[d1]+b2[d1];
  bool e0 = (d0 & 1) == 0;
  xs1[base+d0] = f2b(e0 ? n2a : n1a);  xs1[base+d1] = f2b(e0 ? n2b : n1b);
  xs2[base+d0] = f2b(e0 ? n1a : n2a);  xs2[base+d1] = f2b(e0 ? n1b : n2b);
}

// ---------------- K2: xz = x @ W_in via MFMA 32x32x16 ----------------
// grid (256, 4, 2), 256 thr = 4 waves; wave computes 32 rows x 32 cols, K=128.
__global__ void k_inproj(const bf16* __restrict__ xs1, const bf16* __restrict__ xs2,
                         const bf16* __restrict__ Wt_in, float* __restrict__ xz){
  const int s = blockIdx.z;
  const int wave = threadIdx.x >> 6, lane = threadIdx.x & 63;
  const int row0 = blockIdx.x*32, col0 = blockIdx.y*128 + wave*32;
  const bf16* A  = s ? xs2 : xs1;
  const bf16* Bt = Wt_in + (size_t)s*WIN_SZ;
  const int m = lane & 31, half = lane >> 5;
  const bf16* ap = A  + (size_t)(row0+m)*128 + half*8;
  const bf16* bp = Bt + (size_t)(col0+m)*128 + half*8;
  f32x16 acc;
  #pragma unroll
  for (int i=0;i<16;i++) acc[i]=0.f;
  #pragma unroll
  for (int kk=0;kk<8;kk++){
    short8 af = *(const short8*)(ap + kk*16);
    short8 bf = *(const short8*)(bp + kk*16);
    acc = __builtin_amdgcn_mfma_f32_32x32x16_bf16(af, bf, acc, 0, 0, 0);
  }
  float* o = xz + (size_t)s*NROW*512;
  #pragma unroll
  for (int r=0;r<16;r++){
    int rl = (r&3) + 8*(r>>2) + 4*half;
    o[(size_t)(row0+rl)*512 + col0 + m] = acc[r];
  }
}

// ---------------- K3a: depthwise conv4 + silu -> xcb (bf16) ----------------
__global__ void k_conv(const float* __restrict__ xz,
                       const float* __restrict__ cw1, const float* __restrict__ cb1,
                       const float* __restrict__ cw2, const float* __restrict__ cb2,
                       bf16* __restrict__ xcb){
  const int row = blockIdx.x, s = blockIdx.y, d = threadIdx.x;
  const int b = row >> 12, t = row & (NN-1);
  const float* xp = xz + (size_t)s*NROW*512;
  const float* cw = s?cw2:cw1; const float* cb = s?cb2:cb1;
  float acc = cb[d];
  #pragma unroll
  for (int k=0;k<4;k++){
    int tt = t - 3 + k;
    if (tt >= 0) acc = fmaf(xp[(size_t)(b*NN+tt)*512 + d], cw[d*4+k], acc);
  }
  xcb[(size_t)s*NROW*256 + (size_t)row*256 + d] = f2b(siluf(acc));
}

// ---------------- K3b: xd = xc @ W_x via MFMA 16x16x32 (N padded to 48) ----
// grid (128, 3, 2), 256 thr = 4 waves; wave = 16 rows x 16 cols, K=256.
__global__ void k_xdbl(const bf16* __restrict__ xcb, const bf16* __restrict__ Wt_x,
                       float* __restrict__ xd){
  const int s = blockIdx.z;
  const int wave = threadIdx.x >> 6, lane = threadIdx.x & 63;
  const int row0 = (blockIdx.x*4 + wave)*16, col0 = blockIdx.y*16;
  const bf16* A  = xcb + (size_t)s*NROW*256;
  const bf16* Bt = Wt_x + (size_t)s*WX_SZ;
  const int m = lane & 15, q = lane >> 4;
  const bf16* ap = A  + (size_t)(row0+m)*256 + q*8;
  const bf16* bp = Bt + (size_t)(col0+m)*256 + q*8;
  f32x4 acc;
  #pragma unroll
  for (int i=0;i<4;i++) acc[i]=0.f;
  #pragma unroll
  for (int kk=0;kk<8;kk++){
    short8 af = *(const short8*)(ap + kk*32);
    short8 bf = *(const short8*)(bp + kk*32);
    acc = __builtin_amdgcn_mfma_f32_16x16x32_bf16(af, bf, acc, 0, 0, 0);
  }
  float* xds = xd + (size_t)s*NROW*XDP;
  #pragma unroll
  for (int r=0;r<4;r++){
    int rl = q*4 + r;
    xds[(size_t)(row0+rl)*XDP + col0 + m] = acc[r];
  }
}

// ---------------- K3c: dt = softplus(dt_r @ W_dt + bias) ----------------
__global__ void k_dt(const float* __restrict__ xd,
                     const float* __restrict__ Wdt1, const float* __restrict__ dtb1,
                     const float* __restrict__ Wdt2, const float* __restrict__ dtb2,
                     float* __restrict__ dtg){
  const int row = blockIdx.x, s = blockIdx.y, d = threadIdx.x;
  const float* xr = xd + (size_t)s*NROW*XDP + (size_t)row*XDP;   // block-uniform
  const float* Wdt = s?Wdt2:Wdt1; const float* dtb = s?dtb2:dtb1;
  float acc = dtb[d];
  #pragma unroll
  for (int r=0;r<DTR;r++) acc = fmaf(xr[r], Wdt[r*256+d], acc);
  dtg[(size_t)s*NROW*256 + (size_t)row*256 + d] = softplusf(acc);
}

// ---------------- K4a: local chunk scan ----------------
// grid (NC, 4, 4), 256 thr = 64 d x 4 si-groups; lane owns 4 states.
__global__ void k_scan_local(const float* __restrict__ dtg, const bf16* __restrict__ xcb,
                             const float* __restrict__ xd,
                             const float* __restrict__ Alog1, const float* __restrict__ Alog2,
                             float* __restrict__ Aprod, float* __restrict__ Sfin){
  const int c = blockIdx.x, dtile = blockIdx.y, sb = blockIdx.z;
  const int s = sb >> 1, b = sb & 1;
  const int tid = threadIdx.x;
  const int sq = tid & 3, dl = tid >> 2;
  const int d = dtile*64 + dl;
  const float* dtp = dtg + (size_t)s*NROW*256 + (size_t)b*NN*256 + (size_t)c*CL*256 + d;
  const bf16*  xcp = xcb + (size_t)s*NROW*256 + (size_t)b*NN*256 + (size_t)c*CL*256 + d;
  const float* xdp = xd  + (size_t)s*NROW*XDP + (size_t)b*NN*XDP + (size_t)c*CL*XDP + 8 + 4*sq;
  const float* Alog = s?Alog2:Alog1;
  float A0 = -__expf(Alog[d*16 + 4*sq + 0]);
  float A1 = -__expf(Alog[d*16 + 4*sq + 1]);
  float A2 = -__expf(Alog[d*16 + 4*sq + 2]);
  float A3 = -__expf(Alog[d*16 + 4*sq + 3]);
  float h0=0.f,h1=0.f,h2=0.f,h3=0.f,sdt=0.f;
  #pragma unroll 4
  for (int tt=0;tt<CL;tt++){
    float dtv = dtp[tt*256];
    float xcv = b2f(xcp[tt*256]);
    float4 bm = *(const float4*)(xdp + tt*XDP);
    float coef = dtv*xcv;
    sdt += dtv;
    h0 = fmaf(__expf(dtv*A0), h0, coef*bm.x);
    h1 = fmaf(__expf(dtv*A1), h1, coef*bm.y);
    h2 = fmaf(__expf(dtv*A2), h2, coef*bm.z);
    h3 = fmaf(__expf(dtv*A3), h3, coef*bm.w);
  }
  const size_t idx = ((size_t)(sb*NC + c)*256 + d)*16 + 4*sq;
  *(float4*)&Aprod[idx] = make_float4(__expf(A0*sdt),__expf(A1*sdt),__expf(A2*sdt),__expf(A3*sdt));
  *(float4*)&Sfin[idx]  = make_float4(h0,h1,h2,h3);
}

// ---------------- K4b: inter-chunk carry ----------------
__global__ void k_scan_carry(const float* __restrict__ Aprod, const float* __restrict__ Sfin,
                             float* __restrict__ Hinit){
  const int g = blockIdx.x*256 + threadIdx.x;
  const int sb = g >> 12;
  const int rem = g & 4095;
  float h = 0.f;
  #pragma unroll 4
  for (int c=0;c<NC;c++){
    const size_t idx = (size_t)(sb*NC + c)*4096 + rem;
    float A = Aprod[idx];
    float S = Sfin[idx];
    Hinit[idx] = h;
    h = fmaf(A, h, S);
  }
}

// ---------------- K4c: final scan + fused epilogue, v -> bf16 in xz --------
__global__ void k_scan_final(const float* __restrict__ dtg, const bf16* __restrict__ xcb,
                             const float* __restrict__ xd,
                             const float* __restrict__ Alog1, const float* __restrict__ Alog2,
                             const float* __restrict__ D1, const float* __restrict__ D2,
                             const float* __restrict__ Hinit, float* __restrict__ xz){
  const int c = blockIdx.x, dtile = blockIdx.y, sb = blockIdx.z;
  const int s = sb >> 1, b = sb & 1;
  const int tid = threadIdx.x;
  const int sq = tid & 3, dl = tid >> 2;
  const int d = dtile*64 + dl;
  const float* dtp = dtg + (size_t)s*NROW*256 + (size_t)b*NN*256 + (size_t)c*CL*256 + d;
  const bf16*  xcp = xcb + (size_t)s*NROW*256 + (size_t)b*NN*256 + (size_t)c*CL*256 + d;
  const float* xdp = xd  + (size_t)s*NROW*XDP + (size_t)b*NN*XDP + (size_t)c*CL*XDP + 8 + 4*sq;
  float* yq = xz + (size_t)s*NROW*512 + (size_t)b*NN*512 + (size_t)c*CL*512;
  const float* Alog = s?Alog2:Alog1;
  const float Dd = (s?D2:D1)[d];
  float A0 = -__expf(Alog[d*16 + 4*sq + 0]);
  float A1 = -__expf(Alog[d*16 + 4*sq + 1]);
  float A2 = -__expf(Alog[d*16 + 4*sq + 2]);
  float A3 = -__expf(Alog[d*16 + 4*sq + 3]);
  float4 hv = *(const float4*)&Hinit[((size_t)(sb*NC + c)*256 + d)*16 + 4*sq];
  float h0=hv.x,h1=hv.y,h2=hv.z,h3=hv.w;
  #pragma unroll 4
  for (int tt=0;tt<CL;tt++){
    float dtv = dtp[tt*256];
    float xcv = b2f(xcp[tt*256]);
    float4 bm = *(const float4*)(xdp + tt*XDP);
    float4 cm = *(const float4*)(xdp + tt*XDP + 16);
    float coef = dtv*xcv;
    h0 = fmaf(__expf(dtv*A0), h0, coef*bm.x);
    h1 = fmaf(__expf(dtv*A1), h1, coef*bm.y);
    h2 = fmaf(__expf(dtv*A2), h2, coef*bm.z);
    h3 = fmaf(__expf(dtv*A3), h3, coef*bm.w);
    float y = h0*cm.x + h1*cm.y + h2*cm.z + h3*cm.w;
    y += __shfl_xor(y, 1, 4);
    y += __shfl_xor(y, 2, 4);
    if (sq == 0){
      float zv = yq[tt*512 + 256 + d];
      bf16* vrow = (bf16*)(yq + tt*512);          // v stored bf16 in xp half
      vrow[d] = f2b(fmaf(xcv, Dd, y) * siluf(zv));
    }
  }
}

// ---------------- K5: out = v @ W_out via MFMA 32x32x16 ----------------
// grid (256, 2), 256 thr = 4 waves; wave = 32 rows x 32 cols, K=256.
__global__ void k_out(const float* __restrict__ xz, const bf16* __restrict__ Wt_out,
                      float* __restrict__ out){
  const int s = blockIdx.y;
  const int wave = threadIdx.x >> 6, lane = threadIdx.x & 63;
  const int row0 = blockIdx.x*32, col0 = wave*32;
  const bf16* vbs = (const bf16*)(xz + (size_t)s*NROW*512);   // row pitch 1024 bf16
  const bf16* Bt = Wt_out + (size_t)s*WOUT_SZ;
  const int m = lane & 31, half = lane >> 5;
  const bf16* ap = vbs + (size_t)(row0+m)*1024 + half*8;
  const bf16* bp = Bt  + (size_t)(col0+m)*256  + half*8;
  f32x16 acc;
  #pragma unroll
  for (int i=0;i<16;i++) acc[i]=0.f;
  #pragma unroll
  for (int kk=0;kk<16;kk++){
    short8 af = *(const short8*)(ap + kk*16);
    short8 bf = *(const short8*)(bp + kk*16);
    acc = __builtin_amdgcn_mfma_f32_32x32x16_bf16(af, bf, acc, 0, 0, 0);
  }
  float* o = out + (size_t)s*SOUT;
  #pragma unroll
  for (int r=0;r<16;r++){
    int rl = (r&3) + 8*(r>>2) + 4*half;
    o[(size_t)(row0+rl)*128 + col0 + m] = acc[r];
  }
}

extern "C" void kernel_launch(void* const* d_in, const int* in_sizes, int n_in,
                              void* d_out, int out_size, void* d_ws, size_t ws_size,
                              hipStream_t stream) {
  const float* I1   = (const float*)d_in[0];
  const float* I2   = (const float*)d_in[1];
  const float* I1r  = (const float*)d_in[2];
  const float* I2r  = (const float*)d_in[3];
  const float* ln1w = (const float*)d_in[4];
  const float* ln1b = (const float*)d_in[5];
  const float* ln2w = (const float*)d_in[6];
  const float* ln2b = (const float*)d_in[7];
  const float* Win1 = (const float*)d_in[8];
  const float* cw1  = (const float*)d_in[9];
  const float* cb1  = (const float*)d_in[10];
  const float* Wx1  = (const float*)d_in[11];
  const float* Wdt1 = (const float*)d_in[12];
  const float* dtb1 = (const float*)d_in[13];
  const float* Al1  = (const float*)d_in[14];
  const float* D1   = (const float*)d_in[15];
  const float* Wo1  = (const float*)d_in[16];
  const float* Win2 = (const float*)d_in[17];
  const float* cw2  = (const float*)d_in[18];
  const float* cb2  = (const float*)d_in[19];
  const float* Wx2  = (const float*)d_in[20];
  const float* Wdt2 = (const float*)d_in[21];
  const float* dtb2 = (const float*)d_in[22];
  const float* Al2  = (const float*)d_in[23];
  const float* D2   = (const float*)d_in[24];
  const float* Wo2  = (const float*)d_in[25];
  float* out = (float*)d_out;

  float* ws = (float*)d_ws;
  float* xz    = ws;                                  // 8M floats (32 MB)
  float* dtg   = xz   + (size_t)2*NROW*512;           // 4M floats
  float* xd    = dtg  + (size_t)2*NROW*256;           // 2*8192*48 = 786432
  float* Aprod = xd   + (size_t)2*NROW*XDP;           // 1M floats
  float* Sfin  = Aprod+ (size_t)4*NC*4096/4*4;        // 1M floats (4*64*4096)
  // NB: Aprod/Sfin size = 4 sb * 64 c * 4096 = 1,048,576 each
  bf16* xcb    = (bf16*)(Sfin + (size_t)4*NC*4096);   // 4M bf16 (2M float slots)
  bf16* xs1b   = (bf16*)((float*)xcb + (size_t)2*NROW*256/2); // 1M bf16
  bf16* xs2b   = xs1b + (size_t)NROW*DIM;             // 1M bf16
  bf16* Wt_in  = xs2b + (size_t)NROW*DIM;             // 131072 bf16
  bf16* Wt_out = Wt_in + (size_t)2*WIN_SZ;            // 65536 bf16
  bf16* Wt_x   = Wt_out + (size_t)2*WOUT_SZ;          // 24576 bf16
  float* Hinit = out;                                 // 1M floats scratch until k_out

  k_wconv<<<dim3(864), dim3(256), 0, stream>>>(Win1, Win2, Wo1, Wo2, Wx1, Wx2,
                                               Wt_in, Wt_out, Wt_x);
  k_ln_swap<<<dim3(NROW), dim3(64), 0, stream>>>(I1, I2, I1r, I2r, ln1w, ln1b, ln2w, ln2b,
                                                 out, xs1b, xs2b);
  k_inproj<<<dim3(256,4,2), dim3(256), 0, stream>>>(xs1b, xs2b, Wt_in, xz);
  k_conv<<<dim3(NROW,2), dim3(256), 0, stream>>>(xz, cw1, cb1, cw2, cb2, xcb);
  k_xdbl<<<dim3(128,3,2), dim3(256), 0, stream>>>(xcb, Wt_x, xd);
  k_dt<<<dim3(NROW,2), dim3(256), 0, stream>>>(xd, Wdt1, dtb1, Wdt2, dtb2, dtg);
  k_scan_local<<<dim3(NC,4,4), dim3(256), 0, stream>>>(dtg, xcb, xd, Al1, Al2, Aprod, Sfin);
  k_scan_carry<<<dim3(64), dim3(256), 0, stream>>>(Aprod, Sfin, Hinit);
  k_scan_final<<<dim3(NC,4,4), dim3(256), 0, stream>>>(dtg, xcb, xd, Al1, Al2, D1, D2, Hinit, xz);
  k_out<<<dim3(256,2), dim3(256), 0, stream>>>(xz, Wt_out, out);
}

// Round 6
// 247.021 us; speedup vs baseline: 1.4385x; 1.1015x over previous
//
#include <hip/hip_runtime.h>
#include <hip/hip_bf16.h>
#include <math.h>

#define BB 2
#define NN 4096
#define DIM 128
#define DIN 256
#define DST 16
#define DTR 8
#define NROW (BB*NN)          // 8192
#define SOUT (BB*NN*DIM)      // 1048576
#define NC 128                // chunks per sequence
#define CL 32                 // chunk length
#define XDP 48                // xd row pitch (40 used + 8 pad)
#define EPSF 1e-5f

typedef __hip_bfloat16 bf16;
typedef __attribute__((ext_vector_type(8))) short short8;     // 8 bf16 (4 VGPR)
typedef __attribute__((ext_vector_type(16))) float f32x16;
typedef __attribute__((ext_vector_type(4))) float f32x4;

__device__ __forceinline__ float siluf(float x){ return x / (1.f + __expf(-x)); }
__device__ __forceinline__ float softplusf(float x){ return fmaxf(x,0.f) + log1pf(__expf(-fabsf(x))); }
__device__ __forceinline__ float b2f(bf16 x){ return __bfloat162float(x); }
__device__ __forceinline__ bf16 f2b(float x){ return __float2bfloat16(x); }

// ---------------- K0: weights -> bf16, transposed to [N][K] ----------------
#define WIN_SZ (512*128)
#define WOUT_SZ (128*256)
#define WX_SZ (48*256)
__global__ void k_wconv(const float* __restrict__ Win1, const float* __restrict__ Win2,
                        const float* __restrict__ Wo1,  const float* __restrict__ Wo2,
                        const float* __restrict__ Wx1,  const float* __restrict__ Wx2,
                        bf16* __restrict__ Wt_in, bf16* __restrict__ Wt_out, bf16* __restrict__ Wt_x){
  int id = blockIdx.x*256 + threadIdx.x;
  if (id < 2*WIN_SZ){
    int s = id / WIN_SZ, r = id % WIN_SZ;
    int n = r >> 7, k = r & 127;                 // W_in shape 128x512
    Wt_in[id] = f2b((s?Win2:Win1)[k*512 + n]);
  } else if (id < 2*WIN_SZ + 2*WOUT_SZ){
    int j = id - 2*WIN_SZ;
    int s = j / WOUT_SZ, r = j % WOUT_SZ;
    int n = r >> 8, k = r & 255;                 // W_out shape 256x128
    Wt_out[j] = f2b((s?Wo2:Wo1)[k*128 + n]);
  } else if (id < 2*WIN_SZ + 2*WOUT_SZ + 2*WX_SZ){
    int j = id - 2*WIN_SZ - 2*WOUT_SZ;
    int s = j / WX_SZ, r = j % WX_SZ;
    int n = r >> 8, k = r & 255;                 // W_x shape 256x40, pad n>=40 with 0
    Wt_x[j] = f2b(n < 40 ? (s?Wx2:Wx1)[k*40 + n] : 0.f);
  }
}

// ---------------- K1: residual add + LN + channel swap (xs -> bf16) --------
__global__ void k_ln_swap(const float* __restrict__ I1, const float* __restrict__ I2,
                          const float* __restrict__ I1r, const float* __restrict__ I2r,
                          const float* __restrict__ w1, const float* __restrict__ b1,
                          const float* __restrict__ w2, const float* __restrict__ b2,
                          float* __restrict__ out, bf16* __restrict__ xs1, bf16* __restrict__ xs2){
  const int row = blockIdx.x;
  const int tid = threadIdx.x;
  const int d0 = tid, d1 = tid + 64;
  const int base = row * DIM;
  float r1a = I1[base+d0] + I1r[base+d0];
  float r1b = I1[base+d1] + I1r[base+d1];
  float r2a = I2[base+d0] + I2r[base+d0];
  float r2b = I2[base+d1] + I2r[base+d1];
  out[2*SOUT+base+d0]=r1a; out[2*SOUT+base+d1]=r1b;
  out[3*SOUT+base+d0]=r2a; out[3*SOUT+base+d1]=r2b;
  float s1=r1a+r1b, q1=fmaf(r1a,r1a,r1b*r1b);
  float s2=r2a+r2b, q2=fmaf(r2a,r2a,r2b*r2b);
  #pragma unroll
  for (int m=32;m;m>>=1){
    s1+=__shfl_xor(s1,m,64); q1+=__shfl_xor(q1,m,64);
    s2+=__shfl_xor(s2,m,64); q2+=__shfl_xor(q2,m,64);
  }
  const float inv = 1.f/128.f;
  float mu1=s1*inv, mu2=s2*inv;
  float var1=q1*inv-mu1*mu1, var2=q2*inv-mu2*mu2;
  float is1=rsqrtf(var1+EPSF), is2=rsqrtf(var2+EPSF);
  float n1a=(r1a-mu1)*is1*w1[d0]+b1[d0];
  float n1b=(r1b-mu1)*is1*w1[d1]+b1[d1];
  float n2a=(r2a-mu2)*is2*w2[d0]+b2[d0];
  float n2b=(r2b-mu2)*is2*w2[d1]+b2[d1];
  bool e0 = (d0 & 1) == 0;
  xs1[base+d0] = f2b(e0 ? n2a : n1a);  xs1[base+d1] = f2b(e0 ? n2b : n1b);
  xs2[base+d0] = f2b(e0 ? n1a : n2a);  xs2[base+d1] = f2b(e0 ? n1b : n2b);
}

// ---------------- K2: xz = x @ W_in via MFMA 32x32x16, bf16 out ------------
// grid (256, 4, 2), 256 thr = 4 waves; wave computes 32 rows x 32 cols, K=128.
__global__ void k_inproj(const bf16* __restrict__ xs1, const bf16* __restrict__ xs2,
                         const bf16* __restrict__ Wt_in, bf16* __restrict__ xzb){
  const int s = blockIdx.z;
  const int wave = threadIdx.x >> 6, lane = threadIdx.x & 63;
  const int row0 = blockIdx.x*32, col0 = blockIdx.y*128 + wave*32;
  const bf16* A  = s ? xs2 : xs1;
  const bf16* Bt = Wt_in + (size_t)s*WIN_SZ;
  const int m = lane & 31, half = lane >> 5;
  const bf16* ap = A  + (size_t)(row0+m)*128 + half*8;
  const bf16* bp = Bt + (size_t)(col0+m)*128 + half*8;
  f32x16 acc;
  #pragma unroll
  for (int i=0;i<16;i++) acc[i]=0.f;
  #pragma unroll
  for (int kk=0;kk<8;kk++){
    short8 af = *(const short8*)(ap + kk*16);
    short8 bf = *(const short8*)(bp + kk*16);
    acc = __builtin_amdgcn_mfma_f32_32x32x16_bf16(af, bf, acc, 0, 0, 0);
  }
  bf16* o = xzb + (size_t)s*NROW*512;
  #pragma unroll
  for (int r=0;r<16;r++){
    int rl = (r&3) + 8*(r>>2) + 4*half;
    o[(size_t)(row0+rl)*512 + col0 + m] = f2b(acc[r]);
  }
}

// ---------------- K3a: depthwise conv4 + silu -> xcb, 8 rows/block ---------
__global__ void k_conv(const bf16* __restrict__ xzb,
                       const float* __restrict__ cw1, const float* __restrict__ cb1,
                       const float* __restrict__ cw2, const float* __restrict__ cb2,
                       bf16* __restrict__ xcb){
  const int rb = blockIdx.x, s = blockIdx.y, d = threadIdx.x;
  const int row0 = rb*8;
  const int b = row0 >> 12, t0 = row0 & (NN-1);
  const bf16* xp = xzb + (size_t)s*NROW*512 + (size_t)b*NN*512 + d;
  const float* cw = s?cw2:cw1; const float* cb = s?cb2:cb1;
  const float w0=cw[d*4], w1=cw[d*4+1], w2=cw[d*4+2], w3=cw[d*4+3];
  const float bias = cb[d];
  float xm3 = (t0>=3)? b2f(xp[(size_t)(t0-3)*512]) : 0.f;
  float xm2 = (t0>=2)? b2f(xp[(size_t)(t0-2)*512]) : 0.f;
  float xm1 = (t0>=1)? b2f(xp[(size_t)(t0-1)*512]) : 0.f;
  bf16* op = xcb + (size_t)s*NROW*256 + (size_t)row0*256 + d;
  #pragma unroll
  for (int i=0;i<8;i++){
    float cur = b2f(xp[(size_t)(t0+i)*512]);
    float acc = bias + xm3*w0 + xm2*w1 + xm1*w2 + cur*w3;
    op[i*256] = f2b(siluf(acc));
    xm3=xm2; xm2=xm1; xm1=cur;
  }
}

// ---------------- K3b: xd = xc @ W_x via MFMA 16x16x32 (N padded to 48) ----
// grid (128, 3, 2), 256 thr = 4 waves; wave = 16 rows x 16 cols, K=256.
__global__ void k_xdbl(const bf16* __restrict__ xcb, const bf16* __restrict__ Wt_x,
                       float* __restrict__ xd){
  const int s = blockIdx.z;
  const int wave = threadIdx.x >> 6, lane = threadIdx.x & 63;
  const int row0 = (blockIdx.x*4 + wave)*16, col0 = blockIdx.y*16;
  const bf16* A  = xcb + (size_t)s*NROW*256;
  const bf16* Bt = Wt_x + (size_t)s*WX_SZ;
  const int m = lane & 15, q = lane >> 4;
  const bf16* ap = A  + (size_t)(row0+m)*256 + q*8;
  const bf16* bp = Bt + (size_t)(col0+m)*256 + q*8;
  f32x4 acc;
  #pragma unroll
  for (int i=0;i<4;i++) acc[i]=0.f;
  #pragma unroll
  for (int kk=0;kk<8;kk++){
    short8 af = *(const short8*)(ap + kk*32);
    short8 bf = *(const short8*)(bp + kk*32);
    acc = __builtin_amdgcn_mfma_f32_16x16x32_bf16(af, bf, acc, 0, 0, 0);
  }
  float* xds = xd + (size_t)s*NROW*XDP;
  #pragma unroll
  for (int r=0;r<4;r++){
    int rl = q*4 + r;
    xds[(size_t)(row0+rl)*XDP + col0 + m] = acc[r];
  }
}

// ---------------- K3c: dt = softplus(dt_r @ W_dt + bias) ----------------
__global__ void k_dt(const float* __restrict__ xd,
                     const float* __restrict__ Wdt1, const float* __restrict__ dtb1,
                     const float* __restrict__ Wdt2, const float* __restrict__ dtb2,
                     float* __restrict__ dtg){
  const int row = blockIdx.x, s = blockIdx.y, d = threadIdx.x;
  const float* xr = xd + (size_t)s*NROW*XDP + (size_t)row*XDP;   // block-uniform
  const float* Wdt = s?Wdt2:Wdt1; const float* dtb = s?dtb2:dtb1;
  float acc = dtb[d];
  #pragma unroll
  for (int r=0;r<DTR;r++) acc = fmaf(xr[r], Wdt[r*256+d], acc);
  dtg[(size_t)s*NROW*256 + (size_t)row*256 + d] = softplusf(acc);
}

// ---------------- K4a: local chunk scan ----------------
// grid (NC, 4, 4), 256 thr = 64 d x 4 si-groups; lane owns 4 states.
__global__ void k_scan_local(const float* __restrict__ dtg, const bf16* __restrict__ xcb,
                             const float* __restrict__ xd,
                             const float* __restrict__ Alog1, const float* __restrict__ Alog2,
                             float* __restrict__ Aprod, float* __restrict__ Sfin){
  const int c = blockIdx.x, dtile = blockIdx.y, sb = blockIdx.z;
  const int s = sb >> 1, b = sb & 1;
  const int tid = threadIdx.x;
  const int sq = tid & 3, dl = tid >> 2;
  const int d = dtile*64 + dl;
  const float* dtp = dtg + (size_t)s*NROW*256 + (size_t)b*NN*256 + (size_t)c*CL*256 + d;
  const bf16*  xcp = xcb + (size_t)s*NROW*256 + (size_t)b*NN*256 + (size_t)c*CL*256 + d;
  const float* xdp = xd  + (size_t)s*NROW*XDP + (size_t)b*NN*XDP + (size_t)c*CL*XDP + 8 + 4*sq;
  const float* Alog = s?Alog2:Alog1;
  float A0 = -__expf(Alog[d*16 + 4*sq + 0]);
  float A1 = -__expf(Alog[d*16 + 4*sq + 1]);
  float A2 = -__expf(Alog[d*16 + 4*sq + 2]);
  float A3 = -__expf(Alog[d*16 + 4*sq + 3]);
  float h0=0.f,h1=0.f,h2=0.f,h3=0.f,sdt=0.f;
  #pragma unroll 4
  for (int tt=0;tt<CL;tt++){
    float dtv = dtp[tt*256];
    float xcv = b2f(xcp[tt*256]);
    float4 bm = *(const float4*)(xdp + tt*XDP);
    float coef = dtv*xcv;
    sdt += dtv;
    h0 = fmaf(__expf(dtv*A0), h0, coef*bm.x);
    h1 = fmaf(__expf(dtv*A1), h1, coef*bm.y);
    h2 = fmaf(__expf(dtv*A2), h2, coef*bm.z);
    h3 = fmaf(__expf(dtv*A3), h3, coef*bm.w);
  }
  const size_t idx = ((size_t)(sb*NC + c)*256 + d)*16 + 4*sq;
  *(float4*)&Aprod[idx] = make_float4(__expf(A0*sdt),__expf(A1*sdt),__expf(A2*sdt),__expf(A3*sdt));
  *(float4*)&Sfin[idx]  = make_float4(h0,h1,h2,h3);
}

// ---------------- K4b: inter-chunk carry ----------------
__global__ void k_scan_carry(const float* __restrict__ Aprod, const float* __restrict__ Sfin,
                             float* __restrict__ Hinit){
  const int g = blockIdx.x*256 + threadIdx.x;
  const int sb = g >> 12;
  const int rem = g & 4095;
  float h = 0.f;
  #pragma unroll 4
  for (int c=0;c<NC;c++){
    const size_t idx = (size_t)(sb*NC + c)*4096 + rem;
    float A = Aprod[idx];
    float S = Sfin[idx];
    Hinit[idx] = h;
    h = fmaf(A, h, S);
  }
}

// ---------------- K4c: final scan + fused epilogue, v -> bf16 in xz --------
__global__ void k_scan_final(const float* __restrict__ dtg, const bf16* __restrict__ xcb,
                             const float* __restrict__ xd,
                             const float* __restrict__ Alog1, const float* __restrict__ Alog2,
                             const float* __restrict__ D1, const float* __restrict__ D2,
                             const float* __restrict__ Hinit, bf16* __restrict__ xzb){
  const int c = blockIdx.x, dtile = blockIdx.y, sb = blockIdx.z;
  const int s = sb >> 1, b = sb & 1;
  const int tid = threadIdx.x;
  const int sq = tid & 3, dl = tid >> 2;
  const int d = dtile*64 + dl;
  const float* dtp = dtg + (size_t)s*NROW*256 + (size_t)b*NN*256 + (size_t)c*CL*256 + d;
  const bf16*  xcp = xcb + (size_t)s*NROW*256 + (size_t)b*NN*256 + (size_t)c*CL*256 + d;
  const float* xdp = xd  + (size_t)s*NROW*XDP + (size_t)b*NN*XDP + (size_t)c*CL*XDP + 8 + 4*sq;
  bf16* yq = xzb + (size_t)s*NROW*512 + (size_t)b*NN*512 + (size_t)c*CL*512;
  const float* Alog = s?Alog2:Alog1;
  const float Dd = (s?D2:D1)[d];
  float A0 = -__expf(Alog[d*16 + 4*sq + 0]);
  float A1 = -__expf(Alog[d*16 + 4*sq + 1]);
  float A2 = -__expf(Alog[d*16 + 4*sq + 2]);
  float A3 = -__expf(Alog[d*16 + 4*sq + 3]);
  float4 hv = *(const float4*)&Hinit[((size_t)(sb*NC + c)*256 + d)*16 + 4*sq];
  float h0=hv.x,h1=hv.y,h2=hv.z,h3=hv.w;
  #pragma unroll 4
  for (int tt=0;tt<CL;tt++){
    float dtv = dtp[tt*256];
    float xcv = b2f(xcp[tt*256]);
    float4 bm = *(const float4*)(xdp + tt*XDP);
    float4 cm = *(const float4*)(xdp + tt*XDP + 16);
    float coef = dtv*xcv;
    h0 = fmaf(__expf(dtv*A0), h0, coef*bm.x);
    h1 = fmaf(__expf(dtv*A1), h1, coef*bm.y);
    h2 = fmaf(__expf(dtv*A2), h2, coef*bm.z);
    h3 = fmaf(__expf(dtv*A3), h3, coef*bm.w);
    float y = h0*cm.x + h1*cm.y + h2*cm.z + h3*cm.w;
    y += __shfl_xor(y, 1, 4);
    y += __shfl_xor(y, 2, 4);
    if (sq == 0){
      float zv = b2f(yq[tt*512 + 256 + d]);
      yq[tt*512 + d] = f2b(fmaf(xcv, Dd, y) * siluf(zv));
    }
  }
}

// ---------------- K5: out = v @ W_out via MFMA 32x32x16 ----------------
// grid (256, 2), 256 thr = 4 waves; wave = 32 rows x 32 cols, K=256.
__global__ void k_out(const bf16* __restrict__ xzb, const bf16* __restrict__ Wt_out,
                      float* __restrict__ out){
  const int s = blockIdx.y;
  const int wave = threadIdx.x >> 6, lane = threadIdx.x & 63;
  const int row0 = blockIdx.x*32, col0 = wave*32;
  const bf16* vbs = xzb + (size_t)s*NROW*512;      // v = first 256 of each 512-row
  const bf16* Bt = Wt_out + (size_t)s*WOUT_SZ;
  const int m = lane & 31, half = lane >> 5;
  const bf16* ap = vbs + (size_t)(row0+m)*512 + half*8;
  const bf16* bp = Bt  + (size_t)(col0+m)*256 + half*8;
  f32x16 acc;
  #pragma unroll
  for (int i=0;i<16;i++) acc[i]=0.f;
  #pragma unroll
  for (int kk=0;kk<16;kk++){
    short8 af = *(const short8*)(ap + kk*16);
    short8 bf = *(const short8*)(bp + kk*16);
    acc = __builtin_amdgcn_mfma_f32_32x32x16_bf16(af, bf, acc, 0, 0, 0);
  }
  float* o = out + (size_t)s*SOUT;
  #pragma unroll
  for (int r=0;r<16;r++){
    int rl = (r&3) + 8*(r>>2) + 4*half;
    o[(size_t)(row0+rl)*128 + col0 + m] = acc[r];
  }
}

extern "C" void kernel_launch(void* const* d_in, const int* in_sizes, int n_in,
                              void* d_out, int out_size, void* d_ws, size_t ws_size,
                              hipStream_t stream) {
  const float* I1   = (const float*)d_in[0];
  const float* I2   = (const float*)d_in[1];
  const float* I1r  = (const float*)d_in[2];
  const float* I2r  = (const float*)d_in[3];
  const float* ln1w = (const float*)d_in[4];
  const float* ln1b = (const float*)d_in[5];
  const float* ln2w = (const float*)d_in[6];
  const float* ln2b = (const float*)d_in[7];
  const float* Win1 = (const float*)d_in[8];
  const float* cw1  = (const float*)d_in[9];
  const float* cb1  = (const float*)d_in[10];
  const float* Wx1  = (const float*)d_in[11];
  const float* Wdt1 = (const float*)d_in[12];
  const float* dtb1 = (const float*)d_in[13];
  const float* Al1  = (const float*)d_in[14];
  const float* D1   = (const float*)d_in[15];
  const float* Wo1  = (const float*)d_in[16];
  const float* Win2 = (const float*)d_in[17];
  const float* cw2  = (const float*)d_in[18];
  const float* cb2  = (const float*)d_in[19];
  const float* Wx2  = (const float*)d_in[20];
  const float* Wdt2 = (const float*)d_in[21];
  const float* dtb2 = (const float*)d_in[22];
  const float* Al2  = (const float*)d_in[23];
  const float* D2   = (const float*)d_in[24];
  const float* Wo2  = (const float*)d_in[25];
  float* out = (float*)d_out;

  float* ws = (float*)d_ws;
  bf16*  xzb   = (bf16*)ws;                           // 8M bf16 = 4M float slots
  float* dtg   = ws + (size_t)4*1024*1024;            // 4M floats
  float* xd    = dtg + (size_t)2*NROW*256;            // 786432 floats
  float* Aprod = xd  + (size_t)2*NROW*XDP;            // 2M floats (4*128*4096)
  float* Sfin  = Aprod + (size_t)4*NC*4096;           // 2M floats
  bf16*  xcb   = (bf16*)(Sfin + (size_t)4*NC*4096);   // 4M bf16 = 2M slots
  bf16*  xs1b  = xcb + (size_t)2*NROW*256;            // 1M bf16
  bf16*  xs2b  = xs1b + (size_t)NROW*DIM;             // 1M bf16
  bf16*  Wt_in = xs2b + (size_t)NROW*DIM;             // 131072 bf16
  bf16*  Wt_out= Wt_in + (size_t)2*WIN_SZ;            // 65536 bf16
  bf16*  Wt_x  = Wt_out + (size_t)2*WOUT_SZ;          // 24576 bf16
  float* Hinit = out;                                 // 2M floats scratch until k_out

  k_wconv<<<dim3(864), dim3(256), 0, stream>>>(Win1, Win2, Wo1, Wo2, Wx1, Wx2,
                                               Wt_in, Wt_out, Wt_x);
  k_ln_swap<<<dim3(NROW), dim3(64), 0, stream>>>(I1, I2, I1r, I2r, ln1w, ln1b, ln2w, ln2b,
                                                 out, xs1b, xs2b);
  k_inproj<<<dim3(256,4,2), dim3(256), 0, stream>>>(xs1b, xs2b, Wt_in, xzb);
  k_conv<<<dim3(NROW/8,2), dim3(256), 0, stream>>>(xzb, cw1, cb1, cw2, cb2, xcb);
  k_xdbl<<<dim3(128,3,2), dim3(256), 0, stream>>>(xcb, Wt_x, xd);
  k_dt<<<dim3(NROW,2), dim3(256), 0, stream>>>(xd, Wdt1, dtb1, Wdt2, dtb2, dtg);
  k_scan_local<<<dim3(NC,4,4), dim3(256), 0, stream>>>(dtg, xcb, xd, Al1, Al2, Aprod, Sfin);
  k_scan_carry<<<dim3(64), dim3(256), 0, stream>>>(Aprod, Sfin, Hinit);
  k_scan_final<<<dim3(NC,4,4), dim3(256), 0, stream>>>(dtg, xcb, xd, Al1, Al2, D1, D2, Hinit, xzb);
  k_out<<<dim3(256,2), dim3(256), 0, stream>>>(xzb, Wt_out, out);
}